// Round 1
// 369.200 us; speedup vs baseline: 1.0139x; 1.0139x over previous
//
#include <hip/hip_runtime.h>

// MHA sigmoid-attention, f32 interface, f16 MFMA internals.
// B=4, S=2048, D=1024, H=16, Dh=64.
// R6: attn key-split x2 (occupancy 16->up-to-32 waves/CU; partial-O add
//     kernel since sigmoid-attn needs no normalization), exp2-fold
//     (log2e folded into Q scale, v_exp_f32 direct), s_setprio around
//     MFMA clusters. GEMMs unchanged from R5b.

typedef _Float16 f16x2 __attribute__((ext_vector_type(2)));
typedef _Float16 f16x4 __attribute__((ext_vector_type(4)));
typedef _Float16 f16x8 __attribute__((ext_vector_type(8)));
typedef __fp16   h16x2 __attribute__((ext_vector_type(2)));
typedef float    f32x4 __attribute__((ext_vector_type(4)));
typedef float    f32x16 __attribute__((ext_vector_type(16)));

typedef __attribute__((address_space(3))) void* lds_vp;
typedef const __attribute__((address_space(1))) void* gbl_vp;

__device__ __forceinline__ void gld_lds16(const void* g, void* l) {
  __builtin_amdgcn_global_load_lds((gbl_vp)g, (lds_vp)l, 16, 0, 0);
}

__device__ __forceinline__ f16x8 cvt8(float4 a, float4 b) {
  return (f16x8){(_Float16)a.x, (_Float16)a.y, (_Float16)a.z, (_Float16)a.w,
                 (_Float16)b.x, (_Float16)b.y, (_Float16)b.z, (_Float16)b.w};
}

__device__ __forceinline__ f16x2 pk2(float a, float b) {
  h16x2 r = __builtin_amdgcn_cvt_pkrtz(a, b);
  return __builtin_bit_cast(f16x2, r);
}

__device__ __forceinline__ float exp2_fast(float x) {
#if __has_builtin(__builtin_amdgcn_exp2f)
  return __builtin_amdgcn_exp2f(x);
#else
  float r;
  asm("v_exp_f32 %0, %1" : "=v"(r) : "v"(x));
  return r;
#endif
}

#define BM 128
#define BN 128
#define BK 32

// ---------------- generic GEMM (R3 core, unchanged) ----------------
template <bool AF16, bool BF16, bool TRANSV, bool OUTF32>
__global__ __launch_bounds__(256) void gemm_bt(const void* __restrict__ Av,
                                               const void* __restrict__ Bv,
                                               const float* __restrict__ bias,
                                               void* __restrict__ Yv,
                                               int M, int N, int K) {
  __shared__ __align__(16) _Float16 sA[BM * BK];
  __shared__ __align__(16) _Float16 sB[BN * BK];

  const int t = threadIdx.x, lane = t & 63, wid = t >> 6;
  const int m0 = blockIdx.x * BM, n0 = blockIdx.y * BN;
  const int wm = (wid >> 1) * 64, wn = (wid & 1) * 64;
  const int lrow = lane & 15, g = lane >> 4;

  f32x4 acc[4][4] = {};

  const int arow = 16 * wid + (lane >> 2);
  const int gq = (lane & 3) ^ ((lane >> 3) & 3);
  _Float16* lA1 = sA + wid * 512;
  _Float16* lA2 = sA + 2048 + wid * 512;
  _Float16* lB1 = sB + wid * 512;
  _Float16* lB2 = sB + 2048 + wid * 512;

  const int mrow = t >> 1, mhalf = t & 1;
  const int mm = (mrow >> 1) & 3;
  const int ch_lo = mrow * 4 + ((2 * mhalf) ^ mm);
  const int ch_hi = ch_lo ^ 1;

  const _Float16* pA16a = nullptr; const _Float16* pA16b = nullptr;
  const float* pA32 = nullptr;
  if constexpr (AF16) {
    const _Float16* A = (const _Float16*)Av;
    pA16a = A + (size_t)(m0 + arow) * K + gq * 8;
    pA16b = A + (size_t)(m0 + 64 + arow) * K + gq * 8;
  } else {
    pA32 = (const float*)Av + (size_t)(m0 + mrow) * K + mhalf * 16;
  }
  const _Float16* pB16a = nullptr; const _Float16* pB16b = nullptr;
  const float* pB32 = nullptr;
  if constexpr (BF16) {
    const _Float16* B = (const _Float16*)Bv;
    pB16a = B + (size_t)(n0 + arow) * K + gq * 8;
    pB16b = B + (size_t)(n0 + 64 + arow) * K + gq * 8;
  } else {
    pB32 = (const float*)Bv + (size_t)(n0 + mrow) * K + mhalf * 16;
  }

  const int xr = g ^ ((lrow >> 1) & 3);

  for (int k0 = 0; k0 < K; k0 += BK) {
    float4 av[4], bv4[4];
    if constexpr (!AF16) {
      const float4* p = (const float4*)(pA32 + k0);
      av[0] = p[0]; av[1] = p[1]; av[2] = p[2]; av[3] = p[3];
    }
    if constexpr (!BF16) {
      const float4* p = (const float4*)(pB32 + k0);
      bv4[0] = p[0]; bv4[1] = p[1]; bv4[2] = p[2]; bv4[3] = p[3];
    }
    __syncthreads();
    if constexpr (AF16) {
      gld_lds16(pA16a + k0, lA1);
      gld_lds16(pA16b + k0, lA2);
    } else {
      *(f16x8*)(sA + ch_lo * 8) = cvt8(av[0], av[1]);
      *(f16x8*)(sA + ch_hi * 8) = cvt8(av[2], av[3]);
    }
    if constexpr (BF16) {
      gld_lds16(pB16a + k0, lB1);
      gld_lds16(pB16b + k0, lB2);
    } else {
      *(f16x8*)(sB + ch_lo * 8) = cvt8(bv4[0], bv4[1]);
      *(f16x8*)(sB + ch_hi * 8) = cvt8(bv4[2], bv4[3]);
    }
    __syncthreads();

    f16x8 af[4], bf[4];
#pragma unroll
    for (int i = 0; i < 4; i++)
      af[i] = *(const f16x8*)(sA + (wm + i * 16 + lrow) * 32 + xr * 8);
#pragma unroll
    for (int j = 0; j < 4; j++)
      bf[j] = *(const f16x8*)(sB + (wn + j * 16 + lrow) * 32 + xr * 8);
#pragma unroll
    for (int i = 0; i < 4; i++)
#pragma unroll
      for (int j = 0; j < 4; j++)
        acc[i][j] = __builtin_amdgcn_mfma_f32_16x16x32_f16(af[i], bf[j], acc[i][j], 0, 0, 0);
  }

  const int orow = g * 4, ocol = lrow;
#pragma unroll
  for (int j = 0; j < 4; j++) {
    const int col = n0 + wn + j * 16 + ocol;
    const float bv = bias[col];
#pragma unroll
    for (int i = 0; i < 4; i++) {
      const int row = m0 + wm + i * 16 + orow;
      if constexpr (TRANSV) {
        _Float16* VT = (_Float16*)Yv;
        int s = row & 2047;
        int sp = (s & ~12) | ((s & 4) << 1) | ((s & 8) >> 1);
        _Float16* dst = VT + (((size_t)(row >> 11) * 16 + (col >> 6)) * 64 + (col & 63)) * 2048 + sp;
        f16x4 v = {(_Float16)(acc[i][j][0] + bv), (_Float16)(acc[i][j][1] + bv),
                   (_Float16)(acc[i][j][2] + bv), (_Float16)(acc[i][j][3] + bv)};
        *(f16x4*)dst = v;
      } else if constexpr (OUTF32) {
        float* Y = (float*)Yv;
#pragma unroll
        for (int r = 0; r < 4; r++) Y[(size_t)(row + r) * N + col] = acc[i][j][r] + bv;
      } else {
        _Float16* Y = (_Float16*)Yv;
#pragma unroll
        for (int r = 0; r < 4; r++) Y[(size_t)(row + r) * N + col] = (_Float16)(acc[i][j][r] + bv);
      }
    }
  }
}

// ---------------- fused QKV projection: N=3072, all-f16 ----------------
__global__ __launch_bounds__(256) void qkv_gemm(const _Float16* __restrict__ Xq,
                                                const _Float16* __restrict__ Xk,
                                                const _Float16* __restrict__ Xv,
                                                const _Float16* __restrict__ W,
                                                const float* __restrict__ bq,
                                                const float* __restrict__ bk,
                                                const float* __restrict__ bv,
                                                _Float16* __restrict__ Qo,
                                                _Float16* __restrict__ Ko,
                                                _Float16* __restrict__ VT) {
  __shared__ __align__(16) _Float16 sA[BM * BK];
  __shared__ __align__(16) _Float16 sB[BN * BK];

  const int t = threadIdx.x, lane = t & 63, wid = t >> 6;
  const int n0g = blockIdx.x * BN, m0 = blockIdx.y * BM;
  const int seg = blockIdx.x >> 3, n0 = n0g & 1023;
  const _Float16* A = (seg == 0) ? Xq : (seg == 1) ? Xk : Xv;
  const float* bias = (seg == 0) ? bq : (seg == 1) ? bk : bv;
  const int K = 1024;

  const int wm = (wid >> 1) * 64, wn = (wid & 1) * 64;
  const int lrow = lane & 15, g = lane >> 4;

  f32x4 acc[4][4] = {};

  const int arow = 16 * wid + (lane >> 2);
  const int gq = (lane & 3) ^ ((lane >> 3) & 3);
  _Float16* lA1 = sA + wid * 512;
  _Float16* lA2 = sA + 2048 + wid * 512;
  _Float16* lB1 = sB + wid * 512;
  _Float16* lB2 = sB + 2048 + wid * 512;

  const _Float16* pA16a = A + (size_t)(m0 + arow) * K + gq * 8;
  const _Float16* pA16b = A + (size_t)(m0 + 64 + arow) * K + gq * 8;
  const _Float16* pB16a = W + (size_t)(n0g + arow) * K + gq * 8;
  const _Float16* pB16b = W + (size_t)(n0g + 64 + arow) * K + gq * 8;

  const int xr = g ^ ((lrow >> 1) & 3);

  for (int k0 = 0; k0 < K; k0 += BK) {
    __syncthreads();
    gld_lds16(pA16a + k0, lA1);
    gld_lds16(pA16b + k0, lA2);
    gld_lds16(pB16a + k0, lB1);
    gld_lds16(pB16b + k0, lB2);
    __syncthreads();

    f16x8 af[4], bf[4];
#pragma unroll
    for (int i = 0; i < 4; i++)
      af[i] = *(const f16x8*)(sA + (wm + i * 16 + lrow) * 32 + xr * 8);
#pragma unroll
    for (int j = 0; j < 4; j++)
      bf[j] = *(const f16x8*)(sB + (wn + j * 16 + lrow) * 32 + xr * 8);
#pragma unroll
    for (int i = 0; i < 4; i++)
#pragma unroll
      for (int j = 0; j < 4; j++)
        acc[i][j] = __builtin_amdgcn_mfma_f32_16x16x32_f16(af[i], bf[j], acc[i][j], 0, 0, 0);
  }

  const int orow = g * 4, ocol = lrow;
#pragma unroll
  for (int j = 0; j < 4; j++) {
    const int col = n0 + wn + j * 16 + ocol;
    const float bvv = bias[col];
#pragma unroll
    for (int i = 0; i < 4; i++) {
      const int row = m0 + wm + i * 16 + orow;
      if (seg == 2) {
        int s = row & 2047;
        int sp = (s & ~12) | ((s & 4) << 1) | ((s & 8) >> 1);
        _Float16* dst = VT + (((size_t)(row >> 11) * 16 + (col >> 6)) * 64 + (col & 63)) * 2048 + sp;
        f16x4 v = {(_Float16)(acc[i][j][0] + bvv), (_Float16)(acc[i][j][1] + bvv),
                   (_Float16)(acc[i][j][2] + bvv), (_Float16)(acc[i][j][3] + bvv)};
        *(f16x4*)dst = v;
      } else {
        _Float16* Y = (seg == 0) ? Qo : Ko;
#pragma unroll
        for (int r = 0; r < 4; r++) Y[(size_t)(row + r) * 1024 + col] = (_Float16)(acc[i][j][r] + bvv);
      }
    }
  }
}

// ---------------- attention: O = sigmoid(Q K^T / 8) V ----------------
// 128 q/block, 4 waves x 32 q. KSPL-way key split: each block covers
// 2048/KSPL keys; partial outputs (plain sums -- sigmoid attn has no
// normalization) land in KSPL contiguous f16 buffers, summed by
// add_halves. Q frags pre-scaled by -0.125*log2(e) so the sigmoid uses
// v_exp_f32 (exp2) directly with no per-score multiply.
#define LDS_ROW 72

template <int KSPL>
__global__ __launch_bounds__(256, 4) void attn_sig(const _Float16* __restrict__ Q,
                                                   const _Float16* __restrict__ K,
                                                   const _Float16* __restrict__ VT,
                                                   _Float16* __restrict__ O) {
  __shared__ __align__(16) _Float16 smem[128 * LDS_ROW];  // 18,432 B
  _Float16* sK = smem;                  // [64][72]
  _Float16* sVT = smem + 64 * LDS_ROW;  // [64][72]

  constexpr int SKEY = 2048 / KSPL;  // keys handled by this block

  const int t = threadIdx.x, lane = t & 63, wid = t >> 6;
  const int l31 = lane & 31, g5 = lane >> 5;
  const int b = blockIdx.z, h = blockIdx.y;
  const int qb = (KSPL == 2) ? (int)(blockIdx.x >> 1) : (int)blockIdx.x;
  const int kh = (KSPL == 2) ? (int)(blockIdx.x & 1) : 0;
  const int q0 = qb * 128;
  const int qw = q0 + wid * 32;

  // Q fragments: B-operand of 32x32x16 (n=q=l31, k=8g5+j).
  // Scale = -1/8 * log2(e) so sacc is directly the exp2 argument.
  f16x8 qf[4];
  {
    const _Float16* qp = Q + (size_t)(b * 2048 + qw + l31) * 1024 + h * 64;
#pragma unroll
    for (int dhc = 0; dhc < 4; dhc++)
      qf[dhc] = *(const f16x8*)(qp + dhc * 16 + g5 * 8) * (_Float16)-0.18033688f;
  }

  f32x16 oacc[2] = {};  // [dht] : O^T[dh][q]

  const int srow = t >> 2, scol = (t & 3) * 16;
  const _Float16* kbase = K + ((size_t)(b * 2048) + kh * SKEY + srow) * 1024 + h * 64 + scol;
  const _Float16* vbase = VT + ((size_t)((b * 16 + h) * 64 + srow)) * 2048 + kh * SKEY + scol;

  // software pipeline: tile kt is in registers when the loop body starts
  uint4 ka = *(const uint4*)kbase;
  uint4 kb = *(const uint4*)(kbase + 8);
  uint4 va = *(const uint4*)vbase;
  uint4 vb = *(const uint4*)(vbase + 8);

  for (int kt = 0; kt < SKEY; kt += 64) {
    __syncthreads();  // prev tile's LDS reads done
    *(uint4*)&sK[srow * LDS_ROW + scol] = ka;
    *(uint4*)&sK[srow * LDS_ROW + scol + 8] = kb;
    *(uint4*)&sVT[srow * LDS_ROW + scol] = va;
    *(uint4*)&sVT[srow * LDS_ROW + scol + 8] = vb;
    __syncthreads();

    const int kt2 = kt + 64;
    if (kt2 < SKEY) {  // issue next tile's loads; latency hides behind compute
      ka = *(const uint4*)(kbase + (size_t)kt2 * 1024);
      kb = *(const uint4*)(kbase + (size_t)kt2 * 1024 + 8);
      va = *(const uint4*)(vbase + kt2);
      vb = *(const uint4*)(vbase + kt2 + 8);
    }

#pragma unroll
    for (int kt32 = 0; kt32 < 2; kt32++) {
      // K fragments: A-operand (m=key=l31, k=8g5+j)
      f16x8 kf[4];
#pragma unroll
      for (int dhc = 0; dhc < 4; dhc++)
        kf[dhc] = *(const f16x8*)&sK[(kt32 * 32 + l31) * LDS_ROW + dhc * 16 + g5 * 8];

      f32x16 sacc = {};
      __builtin_amdgcn_s_setprio(1);
#pragma unroll
      for (int dhc = 0; dhc < 4; dhc++)
        sacc = __builtin_amdgcn_mfma_f32_32x32x16_f16(kf[dhc], qf[dhc], sacc, 0, 0, 0);
      __builtin_amdgcn_s_setprio(0);

      // sigmoid: sacc already = -s*log2(e)/8, so p = rcp(1 + 2^sacc)
      f16x8 pf[2];
#pragma unroll
      for (int G = 0; G < 2; G++) {
        union { f16x8 v; f16x2 h[4]; } u;
#pragma unroll
        for (int pr = 0; pr < 4; pr++) {
          float e0 = exp2_fast(sacc[G * 8 + pr * 2 + 0]);
          float e1 = exp2_fast(sacc[G * 8 + pr * 2 + 1]);
          u.h[pr] = pk2(__builtin_amdgcn_rcpf(1.0f + e0),
                        __builtin_amdgcn_rcpf(1.0f + e1));
        }
        pf[G] = u.v;
      }

      // PV: oacc[dht] += VT-frag * P-frag (32x32x16)
      __builtin_amdgcn_s_setprio(1);
#pragma unroll
      for (int dht = 0; dht < 2; dht++)
#pragma unroll
        for (int G = 0; G < 2; G++) {
          f16x8 vf = *(const f16x8*)&sVT[(dht * 32 + l31) * LDS_ROW + kt32 * 32 + G * 16 + g5 * 8];
          oacc[dht] = __builtin_amdgcn_mfma_f32_32x32x16_f16(vf, pf[G], oacc[dht], 0, 0, 0);
        }
      __builtin_amdgcn_s_setprio(0);
    }
  }

  // epilogue: O^T regs -> LDS [q][dh] -> coalesced global (partial buffer kh)
  _Float16* Ob = O + (size_t)kh * (8192 * 1024);
  __syncthreads();
  _Float16* ep = smem;  // [128][72]
#pragma unroll
  for (int dht = 0; dht < 2; dht++)
#pragma unroll
    for (int c = 0; c < 4; c++) {
      f16x4 o4 = {(_Float16)oacc[dht][4 * c + 0], (_Float16)oacc[dht][4 * c + 1],
                  (_Float16)oacc[dht][4 * c + 2], (_Float16)oacc[dht][4 * c + 3]};
      // dh covered: 8c + 4g5 + (0..3) within dht*32 group
      *(f16x4*)&ep[(wid * 32 + l31) * LDS_ROW + dht * 32 + c * 8 + g5 * 4] = o4;
    }
  __syncthreads();
#pragma unroll
  for (int i = 0; i < 4; i++) {
    const int q = i * 32 + (t >> 3), dhc = t & 7;
    f16x8 row = *(const f16x8*)&ep[q * LDS_ROW + dhc * 8];
    *(f16x8*)(Ob + (size_t)(b * 2048 + q0 + q) * 1024 + h * 64 + dhc * 8) = row;
  }
}

// ---------------- partial-O reduction (key-split halves) ----------------
__global__ __launch_bounds__(256) void add_halves(const _Float16* __restrict__ a,
                                                  const _Float16* __restrict__ b,
                                                  _Float16* __restrict__ o, int n) {
  const int i = (blockIdx.x * 256 + threadIdx.x) * 8;
  if (i >= n) return;
  f16x8 x = *(const f16x8*)(a + i);
  f16x8 y = *(const f16x8*)(b + i);
  *(f16x8*)(o + i) = x + y;
}

// ---------------- f32 -> f16 batch convert ----------------
struct CvtArgs {
  const float* src[7];
  _Float16* dst[7];
  int n[7];
  int cnt;
};

__global__ __launch_bounds__(256) void cvt_f32_f16(CvtArgs a) {
  const int ti = blockIdx.y;
  if (ti >= a.cnt) return;
  const int i = (blockIdx.x * 256 + threadIdx.x) * 8;
  if (i >= a.n[ti]) return;
  const float4* s = (const float4*)(a.src[ti] + i);
  float4 x = s[0], y = s[1];
  *(f16x8*)(a.dst[ti] + i) = cvt8(x, y);
}

extern "C" void kernel_launch(void* const* d_in, const int* in_sizes, int n_in,
                              void* d_out, int out_size, void* d_ws, size_t ws_size,
                              hipStream_t stream) {
  const float* query = (const float*)d_in[0];
  const float* key   = (const float*)d_in[1];
  const float* value = (const float*)d_in[2];
  const float* Wq = (const float*)d_in[3];
  const float* bq = (const float*)d_in[4];
  const float* Wk = (const float*)d_in[5];
  const float* bk = (const float*)d_in[6];
  const float* Wv = (const float*)d_in[7];
  const float* bv = (const float*)d_in[8];
  const float* Wo = (const float*)d_in[9];
  const float* bo = (const float*)d_in[10];
  float* out = (float*)d_out;

  const int D = 1024, M = 8192;
  const size_t MB = 1024 * 1024;
  char* ws = (char*)d_ws;
  dim3 bb(256);

  if (ws_size >= 104 * MB) {
    _Float16* Xq = (_Float16*)(ws + 0 * MB);
    _Float16* Xk = (_Float16*)(ws + 16 * MB);
    _Float16* Xv = (_Float16*)(ws + 32 * MB);
    _Float16* Qp = (_Float16*)(ws + 48 * MB);
    _Float16* Kp = (_Float16*)(ws + 64 * MB);
    _Float16* VT = (_Float16*)(ws + 80 * MB);
    _Float16* Wf = (_Float16*)(ws + 96 * MB);  // [Wq;Wk;Wv;Wo] 4 x 1M f16
    // after qkv_gemm, Xq/Xk/Xv are dead: reuse as AO0/AO1 (contiguous) + AO
    _Float16* AO0 = Xq;
    _Float16* AO1 = Xk;
    _Float16* AO  = Xv;
    CvtArgs ca{};
    ca.src[0] = query; ca.dst[0] = Xq; ca.n[0] = M * D;
    ca.src[1] = key;   ca.dst[1] = Xk; ca.n[1] = M * D;
    ca.src[2] = value; ca.dst[2] = Xv; ca.n[2] = M * D;
    ca.src[3] = Wq; ca.dst[3] = Wf + 0 * 1048576; ca.n[3] = D * D;
    ca.src[4] = Wk; ca.dst[4] = Wf + 1 * 1048576; ca.n[4] = D * D;
    ca.src[5] = Wv; ca.dst[5] = Wf + 2 * 1048576; ca.n[5] = D * D;
    ca.src[6] = Wo; ca.dst[6] = Wf + 3 * 1048576; ca.n[6] = D * D;
    ca.cnt = 7;
    cvt_f32_f16<<<dim3(4096, 7), bb, 0, stream>>>(ca);
    qkv_gemm<<<dim3(24, 64), bb, 0, stream>>>(Xq, Xk, Xv, Wf, bq, bk, bv, Qp, Kp, VT);
    attn_sig<2><<<dim3(32, 16, 4), bb, 0, stream>>>(Qp, Kp, VT, AO0);
    add_halves<<<dim3(4096), bb, 0, stream>>>(AO0, AO1, AO, M * D);
    gemm_bt<true, true, false, true><<<dim3(64, 8), bb, 0, stream>>>(AO, Wf + 3 * 1048576, bo, out, M, D, D);
  } else {
    _Float16* Qp = (_Float16*)(ws + 0 * MB);
    _Float16* Kp = (_Float16*)(ws + 16 * MB);
    _Float16* VT = (_Float16*)(ws + 32 * MB);
    _Float16* AO = (_Float16*)(ws + 48 * MB);
    gemm_bt<false, false, false, false><<<dim3(64, 8), bb, 0, stream>>>(query, Wq, bq, Qp, M, D, D);
    gemm_bt<false, false, false, false><<<dim3(64, 8), bb, 0, stream>>>(key,   Wk, bk, Kp, M, D, D);
    gemm_bt<false, false, true,  false><<<dim3(64, 8), bb, 0, stream>>>(value, Wv, bv, VT, M, D, D);
    attn_sig<1><<<dim3(16, 16, 4), bb, 0, stream>>>(Qp, Kp, VT, AO);
    gemm_bt<true, false, false, true><<<dim3(64, 8), bb, 0, stream>>>(AO, Wo, bo, out, M, D, D);
  }
}